// Round 5
// baseline (361.645 us; speedup 1.0000x reference)
//
#include <hip/hip_runtime.h>
#include <stdint.h>

#define BATCH 256
#define M 512
#define N 512
#define K 128

typedef int int4v __attribute__((ext_vector_type(4)));
typedef float float4v __attribute__((ext_vector_type(4)));

// R5 = R3 with ONE change: the full-line output stores are NONTEMPORAL.
// Completing the 2x2 {cached,nt} x {scatter,full-line} matrix:
//   R0 cached+scatter 361 | R3 cached+fullline 362 | R1 nt+scatter 398 | R5 nt+fullline ?
// Theory: TCC write-allocates output lines with an HBM fetch (+268MB hidden
// FETCH ~ +42us in every cached version; R1's regression = nt + partial-line
// amplification). nt + single-inst-per-128B-line should stream to HBM with
// neither. Everything else (stage, swizzled operand LDS, bf hoist, MFMA,
// LDS store-transpose) is byte-identical to R3.
__global__ __launch_bounds__(512, 2) void bmm_s8s8_f32_kernel(
    const int* __restrict__ A32,       // [BATCH, M, K] int32 (values in [-128,127])
    const int* __restrict__ B32,       // [BATCH, N, K] int32
    const float* __restrict__ alpha_p, // scalar
    float* __restrict__ O)             // [BATCH, M, N] fp32
{
    __shared__ int8_t As[M * K];       // 64 KB
    __shared__ int8_t Bs[N * K];       // 64 KB
    __shared__ float  Scr[8][1024];    // 32 KB: per-wave 16x64 f32 store-transpose

    const int tid = threadIdx.x;
    const int bat = blockIdx.x;

    const int* Ag = A32 + (size_t)bat * (M * K);
    const int* Bg = B32 + (size_t)bat * (N * K);

    // ---- Stage + pack: 16384 dword-groups per matrix.
    // LDS layout: row-major [row][128] int8 with 16B-chunk XOR swizzle:
    //   byte addr = row*128 + (chunk ^ (row & 7))*16 + sub*4
#pragma unroll 4
    for (int i = 0; i < 32; ++i) {
        const int g   = i * 512 + tid;   // dword-group 0..16383
        const int row = g >> 5;          // 32 groups per 128-int32 row
        const int kg  = g & 31;
        const int kc  = kg >> 2;         // 16B chunk 0..7
        const int sub = kg & 3;
        const int kcs = kc ^ (row & 7);

        int4v wa = *(const int4v*)(Ag + (size_t)g * 4);
        int4v wb = *(const int4v*)(Bg + (size_t)g * 4);
        const int pa = (wa.x & 0xff) | ((wa.y & 0xff) << 8) |
                       ((wa.z & 0xff) << 16) | (wa.w << 24);
        const int pb = (wb.x & 0xff) | ((wb.y & 0xff) << 8) |
                       ((wb.z & 0xff) << 16) | (wb.w << 24);
        *(int*)(As + row * 128 + kcs * 16 + sub * 4) = pa;
        *(int*)(Bs + row * 128 + kcs * 16 + sub * 4) = pb;
    }
    __syncthreads();

    const int lane = tid & 63;
    const int wave = tid >> 6;
    const int l15  = lane & 15;
    const int quad = lane >> 4;
    const int sn   = wave; // supertile column (n-offset sn*64)

    // Hoist B fragments for this wave's column strip.
    int4v bf[2][4];
#pragma unroll
    for (int ks = 0; ks < 2; ++ks)
#pragma unroll
        for (int j = 0; j < 4; ++j) {
            const int rb = sn * 64 + j * 16 + l15;
            const int kc = (ks * 4 + quad) ^ (rb & 7);
            bf[ks][j] = *(const int4v*)(Bs + rb * 128 + kc * 16);
        }

    const float alpha = *alpha_p;

    for (int sm = 0; sm < 8; ++sm) {
        int4v af[2][4];
#pragma unroll
        for (int ks = 0; ks < 2; ++ks)
#pragma unroll
            for (int i = 0; i < 4; ++i) {
                const int ra = sm * 64 + i * 16 + l15;
                const int kc = (ks * 4 + quad) ^ (ra & 7);
                af[ks][i] = *(const int4v*)(As + ra * 128 + kc * 16);
            }

        int4v acc[4][4];
#pragma unroll
        for (int i = 0; i < 4; ++i)
#pragma unroll
            for (int j = 0; j < 4; ++j)
                acc[i][j] = (int4v){0, 0, 0, 0};

#pragma unroll
        for (int ks = 0; ks < 2; ++ks)
#pragma unroll
            for (int i = 0; i < 4; ++i)
#pragma unroll
                for (int j = 0; j < 4; ++j)
                    acc[i][j] = __builtin_amdgcn_mfma_i32_16x16x64_i8(
                        af[ks][i], bf[ks][j], acc[i][j], 0, 0, 0);

        // ---- Epilogue: per 16-row i-block, transpose through wave-private
        // LDS scratch; each global store inst covers 4 rows x 256B contiguous
        // (one inst completes each 128B line), issued NONTEMPORAL.
        // Scratch addressing: addr(m, n) = m*64 + (n ^ (((m>>2)&1)<<4)).
#pragma unroll
        for (int i = 0; i < 4; ++i) {
            const int wkey = (quad & 1) << 4; // ((m>>2)&1)<<4 with m = quad*4+r
#pragma unroll
            for (int r = 0; r < 4; ++r) {
                const int m = quad * 4 + r;
#pragma unroll
                for (int j = 0; j < 4; ++j) {
                    const int n = j * 16 + l15;
                    Scr[wave][m * 64 + (n ^ wkey)] = alpha * (float)acc[i][j][r];
                }
            }
            asm volatile("s_waitcnt lgkmcnt(0)" ::: "memory");
            __builtin_amdgcn_sched_barrier(0);
#pragma unroll
            for (int r2 = 0; r2 < 4; ++r2) {
                const int m    = r2 * 4 + quad;
                const int rkey = (r2 & 1) << 4; // ((m>>2)&1)<<4
                const float4v v =
                    *(const float4v*)&Scr[wave][m * 64 + ((l15 * 4) ^ rkey)];
                float* p = O + ((size_t)bat * M + sm * 64 + i * 16 + m) * N +
                           sn * 64 + l15 * 4;
                __builtin_nontemporal_store(v, (float4v*)p);
            }
            // WAR (next i overwrites scratch) safe: DS pipe in-order per wave.
        }
    }
}

extern "C" void kernel_launch(void* const* d_in, const int* in_sizes, int n_in,
                              void* d_out, int out_size, void* d_ws, size_t ws_size,
                              hipStream_t stream) {
    const int*   a     = (const int*)d_in[0];
    const int*   b     = (const int*)d_in[1];
    const float* alpha = (const float*)d_in[2];
    float*       out   = (float*)d_out;

    dim3 grid(BATCH);
    dim3 block(512);
    bmm_s8s8_f32_kernel<<<grid, block, 0, stream>>>(a, b, alpha, out);
}